// Round 1
// baseline (778.948 us; speedup 1.0000x reference)
//
#include <hip/hip_runtime.h>
#include <cmath>

#define NTOT 16384
#define NBATCH 8
#define NPRE 900
#define NPOST 64

// ---------------------------------------------------------------------------
// K1: fused MLP  h = relu(BN(W1@feat + b1)); off = W2@h + b2;
//     writes prop_out[b][n][4] = {xyz+off[0:3], off[3]} directly into d_out.
// fp32 GEMM, 128 rows x 128 cols tile, 8x8 per-thread, BK=64.
// ---------------------------------------------------------------------------
__global__ __launch_bounds__(256) void mlp_kernel(
    const float* __restrict__ feat, const float* __restrict__ xyz,
    const float* __restrict__ W1, const float* __restrict__ b1,
    const float* __restrict__ gamma, const float* __restrict__ beta,
    const float* __restrict__ rmean, const float* __restrict__ rvar,
    const float* __restrict__ W2, const float* __restrict__ b2,
    float* __restrict__ prop) {
  __shared__ float As[64][128];   // [k][m]  32 KB
  __shared__ float Bs[64][128];   // [k][n]  32 KB
  const int b  = blockIdx.y;
  const int n0 = blockIdx.x * 128;
  const int tid = threadIdx.x;
  const int tr = tid >> 4, tc = tid & 15;
  const float* fb = feat + (size_t)b * 256 * NTOT;

  float acc[8][8];
#pragma unroll
  for (int r = 0; r < 8; ++r)
#pragma unroll
    for (int c = 0; c < 8; ++c) acc[r][c] = 0.f;

  for (int kt = 0; kt < 4; ++kt) {
    // stage W1 tile transposed: As[k][m] = W1[m][kt*64+k]
    {
      const int m = tid & 127, qh = tid >> 7;
#pragma unroll
      for (int p = 0; p < 8; ++p) {
        const int q = qh + p * 2;                       // 0..15
        const float4 w = *(const float4*)(W1 + (size_t)m * 256 + kt * 64 + q * 4);
        As[q * 4 + 0][m] = w.x; As[q * 4 + 1][m] = w.y;
        As[q * 4 + 2][m] = w.z; As[q * 4 + 3][m] = w.w;
      }
      const int qq = tid & 31, r0 = tid >> 5;
#pragma unroll
      for (int p = 0; p < 8; ++p) {
        const int k = r0 + p * 8;
        *(float4*)(&Bs[k][qq * 4]) =
            *(const float4*)(fb + (size_t)(kt * 64 + k) * NTOT + n0 + qq * 4);
      }
    }
    __syncthreads();
#pragma unroll 8
    for (int k = 0; k < 64; ++k) {
      float a[8], bb[8];
      *(float4*)&a[0]  = *(const float4*)&As[k][tr * 8];
      *(float4*)&a[4]  = *(const float4*)&As[k][tr * 8 + 4];
      *(float4*)&bb[0] = *(const float4*)&Bs[k][tc * 8];
      *(float4*)&bb[4] = *(const float4*)&Bs[k][tc * 8 + 4];
#pragma unroll
      for (int r = 0; r < 8; ++r)
#pragma unroll
        for (int c = 0; c < 8; ++c) acc[r][c] = fmaf(a[r], bb[c], acc[r][c]);
    }
    __syncthreads();
  }

  // epilogue: bias + BN + relu + W2 partials
  float po[4][8];
#pragma unroll
  for (int kk = 0; kk < 4; ++kk)
#pragma unroll
    for (int c = 0; c < 8; ++c) po[kk][c] = 0.f;
#pragma unroll
  for (int r = 0; r < 8; ++r) {
    const int row = tr * 8 + r;
    const float inv = gamma[row] / sqrtf(rvar[row] + 1e-5f);
    const float sh  = beta[row] - rmean[row] * inv;
    const float bb1 = b1[row];
    float w2v[4];
#pragma unroll
    for (int kk = 0; kk < 4; ++kk) w2v[kk] = W2[kk * 128 + row];
#pragma unroll
    for (int c = 0; c < 8; ++c) {
      float h = (acc[r][c] + bb1) * inv + sh;
      h = fmaxf(h, 0.f);
#pragma unroll
      for (int kk = 0; kk < 4; ++kk) po[kk][c] += w2v[kk] * h;
    }
  }
  float* po_lds = &As[0][0];                    // [16][4][128] = 8192 f
#pragma unroll
  for (int kk = 0; kk < 4; ++kk)
#pragma unroll
    for (int c = 0; c < 8; ++c)
      po_lds[((tr * 4 + kk) * 128) + tc * 8 + c] = po[kk][c];
  __syncthreads();
  float* off_lds = &Bs[0][0];                   // [4][128]
#pragma unroll
  for (int it = 0; it < 2; ++it) {
    const int idx = tid + it * 256;
    const int kk = idx >> 7, col = idx & 127;
    float sum = b2[kk];
#pragma unroll
    for (int t2 = 0; t2 < 16; ++t2) sum += po_lds[((t2 * 4 + kk) * 128) + col];
    off_lds[kk * 128 + col] = sum;
  }
  __syncthreads();
  if (tid < 128) {
    const int n = n0 + tid;
    const float* sx = xyz + ((size_t)b * NTOT + n) * 3;
    float4 o;
    o.x = sx[0] + off_lds[0 * 128 + tid];
    o.y = sx[1] + off_lds[1 * 128 + tid];
    o.z = sx[2] + off_lds[2 * 128 + tid];
    o.w = off_lds[3 * 128 + tid];
    *(float4*)(prop + ((size_t)b * NTOT + n) * 4) = o;
  }
}

// ---------------------------------------------------------------------------
// K2: per-batch full bitonic sort (descending sigmoid, tie -> lower index),
//     then select top-900: store box(7)+score, corners(8), area.
// ---------------------------------------------------------------------------
__global__ __launch_bounds__(1024) void sort_kernel(
    const float* __restrict__ cla, const float* __restrict__ prop,
    const float* __restrict__ tmpl, float* __restrict__ selbox,
    float* __restrict__ corners, float* __restrict__ areas) {
  extern __shared__ unsigned long long P[];     // 16384 x u64 = 128 KB
  const int b = blockIdx.x, tid = threadIdx.x;
  for (int n = tid; n < NTOT; n += 1024) {
    const float x = cla[(size_t)b * NTOT + n];
    const float s = 1.0f / (1.0f + expf(-x));   // match XLA logistic expansion
    P[n] = ((unsigned long long)__float_as_uint(s) << 32) |
           (unsigned long long)(0xFFFFFFFFu - (unsigned)n);
  }
  __syncthreads();
  for (int k = 2; k <= NTOT; k <<= 1) {
    for (int j = k >> 1; j > 0; j >>= 1) {
      for (int t = tid; t < NTOT / 2; t += 1024) {
        const int i = ((t & ~(j - 1)) << 1) | (t & (j - 1));
        const int l = i | j;
        const unsigned long long Pi = P[i], Pl = P[l];
        const bool asc = (i & k) == 0;
        if ((Pi < Pl) == asc) { P[i] = Pl; P[l] = Pi; }   // descending overall
      }
      __syncthreads();
    }
  }
  if (tid < NPRE) {
    const unsigned long long p = P[tid];
    const int idx = (int)(0xFFFFFFFFu - (unsigned)(p & 0xFFFFFFFFull));
    const float score = __uint_as_float((unsigned)(p >> 32));
    const float4 pv = *(const float4*)(prop + ((size_t)b * NTOT + idx) * 4);
    const float d3 = tmpl[b * 7 + 3], d4 = tmpl[b * 7 + 4], d5 = tmpl[b * 7 + 5];
    const size_t o8 = ((size_t)b * NPRE + tid) * 8;
    selbox[o8 + 0] = pv.x; selbox[o8 + 1] = pv.y; selbox[o8 + 2] = pv.z;
    selbox[o8 + 3] = d3;   selbox[o8 + 4] = d4;   selbox[o8 + 5] = d5;
    selbox[o8 + 6] = pv.w; selbox[o8 + 7] = score;
    {
#pragma clang fp contract(off)
      const float cu = pv.x, cv = pv.z;
      const float hl = d5 * 0.5f, hw = d4 * 0.5f;
      const float x1 = cu - hl, y1 = cv - hw, x2 = cu + hl, y2 = cv + hw;
      const float cx = (x1 + x2) * 0.5f, cy = (y1 + y2) * 0.5f;
      const float hx = (x2 - x1) * 0.5f, hy = (y2 - y1) * 0.5f;
      const float cr = cosf(pv.w), sr = sinf(pv.w);
      const float lx[4] = {-hx, hx, hx, -hx};
      const float ly[4] = {-hy, -hy, hy, hy};
#pragma unroll
      for (int q = 0; q < 4; ++q) {
        corners[o8 + 2 * q]     = cx + cr * lx[q] - sr * ly[q];
        corners[o8 + 2 * q + 1] = cy + sr * lx[q] + cr * ly[q];
      }
      areas[(size_t)b * NPRE + tid] = (x2 - x1) * (y2 - y1);
    }
  }
}

// ---------------------------------------------------------------------------
// K3: pairwise rotated-IoU -> suppression bitmask (j > i only).
// Sutherland-Hodgman clip, polygon ping-pong in LDS [buf][vert][tid].
// ---------------------------------------------------------------------------
__device__ __forceinline__ float polyclip_area(
    float s0x, float s0y, float s1x, float s1y,
    float s2x, float s2y, float s3x, float s3y,
    const float cjx[4], const float cjy[4], float2* pb, int tid) {
#pragma clang fp contract(off)
  float vx[8], vy[8], d[8];
  vx[0] = s0x; vy[0] = s0y; vx[1] = s1x; vy[1] = s1y;
  vx[2] = s2x; vy[2] = s2y; vx[3] = s3x; vy[3] = s3y;
#pragma unroll
  for (int v = 4; v < 8; ++v) { vx[v] = 0.f; vy[v] = 0.f; }
  int cnt = 4;
  int dst = 0;
#pragma unroll
  for (int e = 0; e < 4; ++e) {
    const float ax = cjx[e], ay = cjy[e];
    const float bx = cjx[(e + 1) & 3], by = cjy[(e + 1) & 3];
    const float nx = bx - ax, ny = by - ay;
    if (e > 0) {
      const int src = dst ^ 1;
#pragma unroll
      for (int v = 0; v < 8; ++v) {
        const float2 p = pb[(src * 8 + v) * 256 + tid];
        vx[v] = p.x; vy[v] = p.y;
      }
    }
#pragma unroll
    for (int v = 0; v < 8; ++v) d[v] = nx * (vy[v] - ay) - ny * (vx[v] - ax);
    int ocnt = 0;
#pragma unroll
    for (int v = 0; v < 8; ++v) {
      const bool valid = v < cnt;
      float nvx, nvy, dn;
      if (v == 7) {            // reference: gather index 8 clamps to 7 if cnt>8
        const bool big = cnt > 8;
        nvx = big ? vx[7] : vx[0]; nvy = big ? vy[7] : vy[0]; dn = big ? d[7] : d[0];
      } else {
        const bool wrap = (v + 1 >= cnt);
        nvx = wrap ? vx[0] : vx[v + 1];
        nvy = wrap ? vy[0] : vy[v + 1];
        dn  = wrap ? d[0]  : d[v + 1];
      }
      const float dc = d[v];
      const bool inc = dc >= 0.f, inn = dn >= 0.f;
      if (valid && inc) {
        if (ocnt < 8) pb[(dst * 8 + ocnt) * 256 + tid] = make_float2(vx[v], vy[v]);
        ++ocnt;                // reference increments even on dropped OOB write
      }
      if (valid && (inc != inn)) {
        const float den = dc - dn;
        const float t = dc / ((den == 0.f) ? 1.0f : den);
        if (ocnt < 8)
          pb[(dst * 8 + ocnt) * 256 + tid] =
              make_float2(vx[v] + t * (nvx - vx[v]), vy[v] + t * (nvy - vy[v]));
        ++ocnt;
      }
    }
    cnt = ocnt;
    dst ^= 1;
  }
  const int fb2 = dst ^ 1;     // buffer written by edge 3
#pragma unroll
  for (int v = 0; v < 8; ++v) {
    const float2 p = pb[(fb2 * 8 + v) * 256 + tid];
    vx[v] = p.x; vy[v] = p.y;
  }
  float s = 0.f;
#pragma unroll
  for (int v = 0; v < 8; ++v) {
    const bool valid = (v < cnt) && (cnt >= 3);
    float jx, jy;
    if (v == 7) {
      const bool big = cnt > 8;
      jx = big ? vx[7] : vx[0]; jy = big ? vy[7] : vy[0];
    } else {
      const bool wrap = (v + 1 >= cnt);
      jx = wrap ? vx[0] : vx[v + 1]; jy = wrap ? vy[0] : vy[v + 1];
    }
    s += valid ? (vx[v] * jy - jx * vy[v]) : 0.f;
  }
  return fabsf(s) * 0.5f;
}

__global__ __launch_bounds__(256) void iou_kernel(
    const float* __restrict__ corners, const float* __restrict__ areas,
    unsigned long long* __restrict__ sup) {
  __shared__ float2 pb[2 * 8 * 256];            // 32 KB ping-pong polygons
  const int i = blockIdx.x, b = blockIdx.y, tid = threadIdx.x;
  const float* ci = corners + ((size_t)b * NPRE + i) * 8;
  const float ai = areas[(size_t)b * NPRE + i];
  const float s0x = ci[0], s0y = ci[1], s1x = ci[2], s1y = ci[3];
  const float s2x = ci[4], s2y = ci[5], s3x = ci[6], s3y = ci[7];
  for (int c = 0; c < 4; ++c) {
    const int j = c * 256 + tid;
    bool bit = false;
    if (j > i && j < NPRE) {
      const float* cj = corners + ((size_t)b * NPRE + j) * 8;
      float cjx[4], cjy[4];
#pragma unroll
      for (int q = 0; q < 4; ++q) { cjx[q] = cj[2 * q]; cjy[q] = cj[2 * q + 1]; }
      const float inter = polyclip_area(s0x, s0y, s1x, s1y, s2x, s2y, s3x, s3y,
                                        cjx, cjy, pb, tid);
      const float aj = areas[(size_t)b * NPRE + j];
      const float iou = inter / fmaxf(ai + aj - inter, 1e-8f);
      bit = iou > 0.85f;
    }
    const unsigned long long m = __ballot(bit);
    if ((tid & 63) == 0)
      sup[((size_t)b * NPRE + i) * 16 + (unsigned)(j >> 6)] = m;
  }
}

// ---------------------------------------------------------------------------
// K4: sequential NMS, one wave per batch; keep words live in lane registers.
// ---------------------------------------------------------------------------
__global__ __launch_bounds__(64) void nms_kernel(
    const unsigned long long* __restrict__ sup,
    unsigned long long* __restrict__ keepw) {
  const int b = blockIdx.x, lane = threadIdx.x;
  unsigned long long kw = 0ull;
  if (lane < 14) kw = ~0ull;
  else if (lane == 14) kw = 0xFull;             // bits 896..899
  const unsigned long long* srow = sup + (size_t)b * NPRE * 16;
  unsigned long long pre = (lane < 16) ? srow[lane] : 0ull;
  for (int i = 0; i < NPRE; ++i) {
    const unsigned long long row = pre;
    if (i + 1 < NPRE) pre = (lane < 16) ? srow[(size_t)(i + 1) * 16 + lane] : 0ull;
    const unsigned long long w = __shfl(kw, i >> 6);
    if ((w >> (i & 63)) & 1ull) kw &= ~row;     // row has only j>i bits
  }
  if (lane < 15) keepw[b * 16 + lane] = kw;
}

// ---------------------------------------------------------------------------
// K5: zero outputs, rank kept boxes, scatter top-64 (boxes, scores, centers).
// ---------------------------------------------------------------------------
__global__ __launch_bounds__(128) void out_kernel(
    const float* __restrict__ selbox,
    const unsigned long long* __restrict__ keepw, float* __restrict__ out) {
  const int b = blockIdx.x, t = threadIdx.x;
  float* retb = out + (size_t)b * (NPOST * 7);
  float* rets = out + (size_t)NBATCH * NPOST * 7 + (size_t)b * NPOST;
  float* cent = out + (size_t)NBATCH * NPOST * 7 + (size_t)NBATCH * NPOST +
                (size_t)NBATCH * NTOT * 4 + (size_t)b * (NPOST * 3);
  for (int q = t; q < NPOST * 7; q += 128) retb[q] = 0.f;
  if (t < NPOST) rets[t] = 0.f;
  for (int q = t; q < NPOST * 3; q += 128) cent[q] = 0.f;
  __syncthreads();
  if (t < 64) {
    const unsigned long long kws = (t < 15) ? keepw[b * 16 + t] : 0ull;
    const int pc = __popcll(kws);
    int inc = pc;
    for (int d2 = 1; d2 < 64; d2 <<= 1) {
      const int up = __shfl_up(inc, d2);
      if (t >= d2) inc += up;
    }
    const int ex = inc - pc;                    // exclusive prefix of kept counts
    for (int it = 0; it < 15; ++it) {           // uniform trip count (shfl safety)
      const int i = t + it * 64;
      const int w = (i >> 6) & 63;
      const unsigned long long kword = __shfl(kws, w);
      const int exw = __shfl(ex, w);
      if (i < NPRE) {
        const int bp = i & 63;
        if ((kword >> bp) & 1ull) {
          const int rank =
              exw + __popcll(kword & (((unsigned long long)1 << bp) - 1ull));
          if (rank < NPOST) {
            const float* sb = selbox + ((size_t)b * NPRE + i) * 8;
#pragma unroll
            for (int c = 0; c < 7; ++c) retb[rank * 7 + c] = sb[c];
            rets[rank] = sb[7];
            cent[rank * 3 + 0] = sb[0];
            cent[rank * 3 + 1] = sb[1];
            cent[rank * 3 + 2] = sb[2];
          }
        }
      }
    }
  }
}

// ---------------------------------------------------------------------------
extern "C" void kernel_launch(void* const* d_in, const int* in_sizes, int n_in,
                              void* d_out, int out_size, void* d_ws, size_t ws_size,
                              hipStream_t stream) {
  const float* xyz   = (const float*)d_in[0];
  const float* feat  = (const float*)d_in[1];
  const float* cla   = (const float*)d_in[2];
  const float* tmpl  = (const float*)d_in[3];
  const float* W1    = (const float*)d_in[4];
  const float* b1    = (const float*)d_in[5];
  const float* gamma = (const float*)d_in[6];
  const float* beta  = (const float*)d_in[7];
  const float* rmean = (const float*)d_in[8];
  const float* rvar  = (const float*)d_in[9];
  const float* W2    = (const float*)d_in[10];
  const float* b2    = (const float*)d_in[11];
  float* out  = (float*)d_out;
  float* prop = out + (size_t)NBATCH * NPOST * 7 + (size_t)NBATCH * NPOST; // 4096

  char* ws = (char*)d_ws;
  float* selbox  = (float*)(ws);                               // 8*900*8*4 = 230400
  float* corners = (float*)(ws + 230400);                      // 230400
  float* areas   = (float*)(ws + 460800);                      // 28800
  unsigned long long* sup   = (unsigned long long*)(ws + 489600);   // 921600
  unsigned long long* keepw = (unsigned long long*)(ws + 1411200);  // 1024

  mlp_kernel<<<dim3(NTOT / 128, NBATCH), 256, 0, stream>>>(
      feat, xyz, W1, b1, gamma, beta, rmean, rvar, W2, b2, prop);

  (void)hipFuncSetAttribute((const void*)sort_kernel,
                            hipFuncAttributeMaxDynamicSharedMemorySize,
                            NTOT * (int)sizeof(unsigned long long));
  sort_kernel<<<NBATCH, 1024, NTOT * sizeof(unsigned long long), stream>>>(
      cla, prop, tmpl, selbox, corners, areas);

  iou_kernel<<<dim3(NPRE, NBATCH), 256, 0, stream>>>(corners, areas, sup);

  nms_kernel<<<NBATCH, 64, 0, stream>>>(sup, keepw);

  out_kernel<<<NBATCH, 128, 0, stream>>>(selbox, keepw, out);
}

// Round 2
// 460.864 us; speedup vs baseline: 1.6902x; 1.6902x over previous
//
#include <hip/hip_runtime.h>
#include <cmath>

#define NTOT 16384
#define NBATCH 8
#define NPRE 900
#define NPOST 64

// ---------------------------------------------------------------------------
// K1: fused MLP  h = relu(BN(W1@feat + b1)); off = W2@h + b2;
//     writes prop_out[b][n][4] = {xyz+off[0:3], off[3]} directly into d_out.
// fp32 GEMM, 128 rows x 128 cols tile, 8x8 per-thread, BK=64.
// ---------------------------------------------------------------------------
__global__ __launch_bounds__(256) void mlp_kernel(
    const float* __restrict__ feat, const float* __restrict__ xyz,
    const float* __restrict__ W1, const float* __restrict__ b1,
    const float* __restrict__ gamma, const float* __restrict__ beta,
    const float* __restrict__ rmean, const float* __restrict__ rvar,
    const float* __restrict__ W2, const float* __restrict__ b2,
    float* __restrict__ prop) {
  __shared__ float As[64][128];   // [k][m]  32 KB
  __shared__ float Bs[64][128];   // [k][n]  32 KB
  const int b  = blockIdx.y;
  const int n0 = blockIdx.x * 128;
  const int tid = threadIdx.x;
  const int tr = tid >> 4, tc = tid & 15;
  const float* fb = feat + (size_t)b * 256 * NTOT;

  float acc[8][8];
#pragma unroll
  for (int r = 0; r < 8; ++r)
#pragma unroll
    for (int c = 0; c < 8; ++c) acc[r][c] = 0.f;

  for (int kt = 0; kt < 4; ++kt) {
    // stage W1 tile transposed: As[k][m] = W1[m][kt*64+k]
    {
      const int m = tid & 127, qh = tid >> 7;
#pragma unroll
      for (int p = 0; p < 8; ++p) {
        const int q = qh + p * 2;                       // 0..15
        const float4 w = *(const float4*)(W1 + (size_t)m * 256 + kt * 64 + q * 4);
        As[q * 4 + 0][m] = w.x; As[q * 4 + 1][m] = w.y;
        As[q * 4 + 2][m] = w.z; As[q * 4 + 3][m] = w.w;
      }
      const int qq = tid & 31, r0 = tid >> 5;
#pragma unroll
      for (int p = 0; p < 8; ++p) {
        const int k = r0 + p * 8;
        *(float4*)(&Bs[k][qq * 4]) =
            *(const float4*)(fb + (size_t)(kt * 64 + k) * NTOT + n0 + qq * 4);
      }
    }
    __syncthreads();
#pragma unroll 8
    for (int k = 0; k < 64; ++k) {
      float a[8], bb[8];
      *(float4*)&a[0]  = *(const float4*)&As[k][tr * 8];
      *(float4*)&a[4]  = *(const float4*)&As[k][tr * 8 + 4];
      *(float4*)&bb[0] = *(const float4*)&Bs[k][tc * 8];
      *(float4*)&bb[4] = *(const float4*)&Bs[k][tc * 8 + 4];
#pragma unroll
      for (int r = 0; r < 8; ++r)
#pragma unroll
        for (int c = 0; c < 8; ++c) acc[r][c] = fmaf(a[r], bb[c], acc[r][c]);
    }
    __syncthreads();
  }

  // epilogue: bias + BN + relu + W2 partials
  float po[4][8];
#pragma unroll
  for (int kk = 0; kk < 4; ++kk)
#pragma unroll
    for (int c = 0; c < 8; ++c) po[kk][c] = 0.f;
#pragma unroll
  for (int r = 0; r < 8; ++r) {
    const int row = tr * 8 + r;
    const float inv = gamma[row] / sqrtf(rvar[row] + 1e-5f);
    const float sh  = beta[row] - rmean[row] * inv;
    const float bb1 = b1[row];
    float w2v[4];
#pragma unroll
    for (int kk = 0; kk < 4; ++kk) w2v[kk] = W2[kk * 128 + row];
#pragma unroll
    for (int c = 0; c < 8; ++c) {
      float h = (acc[r][c] + bb1) * inv + sh;
      h = fmaxf(h, 0.f);
#pragma unroll
      for (int kk = 0; kk < 4; ++kk) po[kk][c] += w2v[kk] * h;
    }
  }
  float* po_lds = &As[0][0];                    // [16][4][128] = 8192 f
#pragma unroll
  for (int kk = 0; kk < 4; ++kk)
#pragma unroll
    for (int c = 0; c < 8; ++c)
      po_lds[((tr * 4 + kk) * 128) + tc * 8 + c] = po[kk][c];
  __syncthreads();
  float* off_lds = &Bs[0][0];                   // [4][128]
#pragma unroll
  for (int it = 0; it < 2; ++it) {
    const int idx = tid + it * 256;
    const int kk = idx >> 7, col = idx & 127;
    float sum = b2[kk];
#pragma unroll
    for (int t2 = 0; t2 < 16; ++t2) sum += po_lds[((t2 * 4 + kk) * 128) + col];
    off_lds[kk * 128 + col] = sum;
  }
  __syncthreads();
  if (tid < 128) {
    const int n = n0 + tid;
    const float* sx = xyz + ((size_t)b * NTOT + n) * 3;
    float4 o;
    o.x = sx[0] + off_lds[0 * 128 + tid];
    o.y = sx[1] + off_lds[1 * 128 + tid];
    o.z = sx[2] + off_lds[2 * 128 + tid];
    o.w = off_lds[3 * 128 + tid];
    *(float4*)(prop + ((size_t)b * NTOT + n) * 4) = o;
  }
}

// ---------------------------------------------------------------------------
// K2: exact top-NPRE selection via 32-bit threshold bisection on sigmoid bits
//     (sigmoid > 0 so fp32 bits are order-isomorphic), then bitonic sort of
//     <=1024 candidates with (keybits<<32 | ~idx) -- identical total order to
//     the reference's stable argsort(-sigmoid).
// ---------------------------------------------------------------------------
__global__ __launch_bounds__(1024) void select_kernel(
    const float* __restrict__ cla, const float* __restrict__ prop,
    const float* __restrict__ tmpl, float* __restrict__ selbox,
    float* __restrict__ corners, float* __restrict__ areas) {
  __shared__ unsigned red[17];
  __shared__ int cnt_lds;
  __shared__ unsigned long long cand[1024];
  const int b = blockIdx.x, tid = threadIdx.x;
  unsigned key[16];
#pragma unroll
  for (int q = 0; q < 16; ++q) {
    const float x = cla[(size_t)b * NTOT + q * 1024 + tid];
    key[q] = __float_as_uint(1.0f / (1.0f + expf(-x)));  // same formula as r0
  }
  // bisect: T = max threshold with count(key >= T) >= NPRE
  unsigned lo = 0u, hi = 0xFFFFFFFFu;
  while (hi - lo > 1u) {
    const unsigned mid = lo + ((hi - lo) >> 1);
    int c = 0;
#pragma unroll
    for (int q = 0; q < 16; ++q) c += (key[q] >= mid) ? 1 : 0;
#pragma unroll
    for (int off = 32; off > 0; off >>= 1) c += __shfl_down(c, off);
    __syncthreads();                       // red[] reuse hazard from prev iter
    if ((tid & 63) == 0) red[tid >> 6] = (unsigned)c;
    __syncthreads();
    if (tid == 0) {
      unsigned s = 0;
      for (int w2 = 0; w2 < 16; ++w2) s += red[w2];
      red[16] = s;
    }
    __syncthreads();
    if (red[16] >= NPRE) lo = mid; else hi = mid;
  }
  const unsigned T = lo;
  if (tid == 0) cnt_lds = 0;
  cand[tid] = 0ull;                        // pad sorts to the end
  __syncthreads();
#pragma unroll
  for (int q = 0; q < 16; ++q) {
    if (key[q] >= T) {
      const int pos = atomicAdd(&cnt_lds, 1);
      if (pos < 1024)
        cand[pos] = ((unsigned long long)key[q] << 32) |
                    (unsigned long long)(0xFFFFFFFFu - (unsigned)(q * 1024 + tid));
    }
  }
  __syncthreads();
  // bitonic sort 1024 u64, descending (same compare convention as round 0)
  for (int k = 2; k <= 1024; k <<= 1) {
    for (int j = k >> 1; j > 0; j >>= 1) {
      if (tid < 512) {
        const int i = ((tid & ~(j - 1)) << 1) | (tid & (j - 1));
        const int l = i | j;
        const unsigned long long Pi = cand[i], Pl = cand[l];
        const bool asc = (i & k) == 0;
        if ((Pi < Pl) == asc) { cand[i] = Pl; cand[l] = Pi; }
      }
      __syncthreads();
    }
  }
  if (tid < NPRE) {
    const unsigned long long p = cand[tid];
    const int idx = (int)(0xFFFFFFFFu - (unsigned)(p & 0xFFFFFFFFull));
    const float score = __uint_as_float((unsigned)(p >> 32));
    const float4 pv = *(const float4*)(prop + ((size_t)b * NTOT + idx) * 4);
    const float d3 = tmpl[b * 7 + 3], d4 = tmpl[b * 7 + 4], d5 = tmpl[b * 7 + 5];
    const size_t o8 = ((size_t)b * NPRE + tid) * 8;
    selbox[o8 + 0] = pv.x; selbox[o8 + 1] = pv.y; selbox[o8 + 2] = pv.z;
    selbox[o8 + 3] = d3;   selbox[o8 + 4] = d4;   selbox[o8 + 5] = d5;
    selbox[o8 + 6] = pv.w; selbox[o8 + 7] = score;
    {
#pragma clang fp contract(off)
      const float cu = pv.x, cv = pv.z;
      const float hl = d5 * 0.5f, hw = d4 * 0.5f;
      const float x1 = cu - hl, y1 = cv - hw, x2 = cu + hl, y2 = cv + hw;
      const float cx = (x1 + x2) * 0.5f, cy = (y1 + y2) * 0.5f;
      const float hx = (x2 - x1) * 0.5f, hy = (y2 - y1) * 0.5f;
      const float cr = cosf(pv.w), sr = sinf(pv.w);
      const float lx[4] = {-hx, hx, hx, -hx};
      const float ly[4] = {-hy, -hy, hy, hy};
#pragma unroll
      for (int q = 0; q < 4; ++q) {
        corners[o8 + 2 * q]     = cx + cr * lx[q] - sr * ly[q];
        corners[o8 + 2 * q + 1] = cy + sr * lx[q] + cr * ly[q];
      }
      areas[(size_t)b * NPRE + tid] = (x2 - x1) * (y2 - y1);
    }
  }
}

// ---------------------------------------------------------------------------
// K3: pairwise rotated-IoU -> suppression bitmask (j > i only).
// Sutherland-Hodgman clip, polygon ping-pong in LDS [buf][vert][tid].
// ---------------------------------------------------------------------------
__device__ __forceinline__ float polyclip_area(
    float s0x, float s0y, float s1x, float s1y,
    float s2x, float s2y, float s3x, float s3y,
    const float cjx[4], const float cjy[4], float2* pb, int tid) {
#pragma clang fp contract(off)
  float vx[8], vy[8], d[8];
  vx[0] = s0x; vy[0] = s0y; vx[1] = s1x; vy[1] = s1y;
  vx[2] = s2x; vy[2] = s2y; vx[3] = s3x; vy[3] = s3y;
#pragma unroll
  for (int v = 4; v < 8; ++v) { vx[v] = 0.f; vy[v] = 0.f; }
  int cnt = 4;
  int dst = 0;
#pragma unroll
  for (int e = 0; e < 4; ++e) {
    const float ax = cjx[e], ay = cjy[e];
    const float bx = cjx[(e + 1) & 3], by = cjy[(e + 1) & 3];
    const float nx = bx - ax, ny = by - ay;
    if (e > 0) {
      const int src = dst ^ 1;
#pragma unroll
      for (int v = 0; v < 8; ++v) {
        const float2 p = pb[(src * 8 + v) * 256 + tid];
        vx[v] = p.x; vy[v] = p.y;
      }
    }
#pragma unroll
    for (int v = 0; v < 8; ++v) d[v] = nx * (vy[v] - ay) - ny * (vx[v] - ax);
    int ocnt = 0;
#pragma unroll
    for (int v = 0; v < 8; ++v) {
      const bool valid = v < cnt;
      float nvx, nvy, dn;
      if (v == 7) {            // reference: gather index 8 clamps to 7 if cnt>8
        const bool big = cnt > 8;
        nvx = big ? vx[7] : vx[0]; nvy = big ? vy[7] : vy[0]; dn = big ? d[7] : d[0];
      } else {
        const bool wrap = (v + 1 >= cnt);
        nvx = wrap ? vx[0] : vx[v + 1];
        nvy = wrap ? vy[0] : vy[v + 1];
        dn  = wrap ? d[0]  : d[v + 1];
      }
      const float dc = d[v];
      const bool inc = dc >= 0.f, inn = dn >= 0.f;
      if (valid && inc) {
        if (ocnt < 8) pb[(dst * 8 + ocnt) * 256 + tid] = make_float2(vx[v], vy[v]);
        ++ocnt;                // reference increments even on dropped OOB write
      }
      if (valid && (inc != inn)) {
        const float den = dc - dn;
        const float t = dc / ((den == 0.f) ? 1.0f : den);
        if (ocnt < 8)
          pb[(dst * 8 + ocnt) * 256 + tid] =
              make_float2(vx[v] + t * (nvx - vx[v]), vy[v] + t * (nvy - vy[v]));
        ++ocnt;
      }
    }
    cnt = ocnt;
    dst ^= 1;
  }
  const int fb2 = dst ^ 1;     // buffer written by edge 3
#pragma unroll
  for (int v = 0; v < 8; ++v) {
    const float2 p = pb[(fb2 * 8 + v) * 256 + tid];
    vx[v] = p.x; vy[v] = p.y;
  }
  float s = 0.f;
#pragma unroll
  for (int v = 0; v < 8; ++v) {
    const bool valid = (v < cnt) && (cnt >= 3);
    float jx, jy;
    if (v == 7) {
      const bool big = cnt > 8;
      jx = big ? vx[7] : vx[0]; jy = big ? vy[7] : vy[0];
    } else {
      const bool wrap = (v + 1 >= cnt);
      jx = wrap ? vx[0] : vx[v + 1]; jy = wrap ? vy[0] : vy[v + 1];
    }
    s += valid ? (vx[v] * jy - jx * vy[v]) : 0.f;
  }
  return fabsf(s) * 0.5f;
}

__global__ __launch_bounds__(256) void iou_kernel(
    const float* __restrict__ corners, const float* __restrict__ areas,
    unsigned long long* __restrict__ sup) {
  __shared__ float2 pb[2 * 8 * 256];            // 32 KB ping-pong polygons
  const int i = blockIdx.x, b = blockIdx.y, tid = threadIdx.x;
  const float* ci = corners + ((size_t)b * NPRE + i) * 8;
  const float ai = areas[(size_t)b * NPRE + i];
  const float s0x = ci[0], s0y = ci[1], s1x = ci[2], s1y = ci[3];
  const float s2x = ci[4], s2y = ci[5], s3x = ci[6], s3y = ci[7];
  for (int c = 0; c < 4; ++c) {
    const int j = c * 256 + tid;
    bool bit = false;
    if (j > i && j < NPRE) {
      const float* cj = corners + ((size_t)b * NPRE + j) * 8;
      float cjx[4], cjy[4];
#pragma unroll
      for (int q = 0; q < 4; ++q) { cjx[q] = cj[2 * q]; cjy[q] = cj[2 * q + 1]; }
      const float inter = polyclip_area(s0x, s0y, s1x, s1y, s2x, s2y, s3x, s3y,
                                        cjx, cjy, pb, tid);
      const float aj = areas[(size_t)b * NPRE + j];
      const float iou = inter / fmaxf(ai + aj - inter, 1e-8f);
      bit = iou > 0.85f;
    }
    const unsigned long long m = __ballot(bit);
    if ((tid & 63) == 0)
      sup[((size_t)b * NPRE + i) * 16 + (unsigned)(j >> 6)] = m;
  }
}

// ---------------------------------------------------------------------------
// K4: sequential NMS. Stage the 900x16-word sup matrix into LDS (1024 thr,
// coalesced), then wave 0 runs the serial pass with a 4-deep statically-
// indexed prefetch (named regs r0..r3, no runtime-indexed array).
// ---------------------------------------------------------------------------
#define NMS_ROWS 904                      // NPRE rounded up + prefetch pad
__global__ __launch_bounds__(1024) void nms_kernel(
    const unsigned long long* __restrict__ sup,
    unsigned long long* __restrict__ keepw) {
  extern __shared__ unsigned long long rows[];   // NMS_ROWS*16*8 = 115,712 B
  const int b = blockIdx.x, tid = threadIdx.x;
  const unsigned long long* srow = sup + (size_t)b * NPRE * 16;
  for (int q = tid; q < NMS_ROWS * 16; q += 1024)
    rows[q] = (q < NPRE * 16) ? srow[q] : 0ull;
  __syncthreads();
  if (tid < 64) {
    const int lane = tid;
    const bool ld = lane < 16;
    unsigned long long kw = 0ull;
    if (lane < 14) kw = ~0ull;
    else if (lane == 14) kw = 0xFull;            // bits 896..899
    unsigned long long r0 = ld ? rows[0 * 16 + lane] : 0ull;
    unsigned long long r1 = ld ? rows[1 * 16 + lane] : 0ull;
    unsigned long long r2 = ld ? rows[2 * 16 + lane] : 0ull;
    unsigned long long r3 = ld ? rows[3 * 16 + lane] : 0ull;
#define NMS_STEP(ii, bufv)                                            \
    {                                                                 \
      const unsigned long long w = __shfl(kw, (ii) >> 6);             \
      if ((w >> ((ii) & 63)) & 1ull) kw &= ~(bufv);                   \
      bufv = ld ? rows[((ii) + 4) * 16 + lane] : 0ull;                \
    }
    for (int i = 0; i < NPRE; i += 4) {
      NMS_STEP(i + 0, r0)
      NMS_STEP(i + 1, r1)
      NMS_STEP(i + 2, r2)
      NMS_STEP(i + 3, r3)
    }
#undef NMS_STEP
    if (lane < 15) keepw[b * 16 + lane] = kw;
  }
}

// ---------------------------------------------------------------------------
// K5: zero outputs, rank kept boxes, scatter top-64 (boxes, scores, centers).
// ---------------------------------------------------------------------------
__global__ __launch_bounds__(128) void out_kernel(
    const float* __restrict__ selbox,
    const unsigned long long* __restrict__ keepw, float* __restrict__ out) {
  const int b = blockIdx.x, t = threadIdx.x;
  float* retb = out + (size_t)b * (NPOST * 7);
  float* rets = out + (size_t)NBATCH * NPOST * 7 + (size_t)b * NPOST;
  float* cent = out + (size_t)NBATCH * NPOST * 7 + (size_t)NBATCH * NPOST +
                (size_t)NBATCH * NTOT * 4 + (size_t)b * (NPOST * 3);
  for (int q = t; q < NPOST * 7; q += 128) retb[q] = 0.f;
  if (t < NPOST) rets[t] = 0.f;
  for (int q = t; q < NPOST * 3; q += 128) cent[q] = 0.f;
  __syncthreads();
  if (t < 64) {
    const unsigned long long kws = (t < 15) ? keepw[b * 16 + t] : 0ull;
    const int pc = __popcll(kws);
    int inc = pc;
    for (int d2 = 1; d2 < 64; d2 <<= 1) {
      const int up = __shfl_up(inc, d2);
      if (t >= d2) inc += up;
    }
    const int ex = inc - pc;                    // exclusive prefix of kept counts
    for (int it = 0; it < 15; ++it) {           // uniform trip count (shfl safety)
      const int i = t + it * 64;
      const int w = (i >> 6) & 63;
      const unsigned long long kword = __shfl(kws, w);
      const int exw = __shfl(ex, w);
      if (i < NPRE) {
        const int bp = i & 63;
        if ((kword >> bp) & 1ull) {
          const int rank =
              exw + __popcll(kword & (((unsigned long long)1 << bp) - 1ull));
          if (rank < NPOST) {
            const float* sb = selbox + ((size_t)b * NPRE + i) * 8;
#pragma unroll
            for (int c = 0; c < 7; ++c) retb[rank * 7 + c] = sb[c];
            rets[rank] = sb[7];
            cent[rank * 3 + 0] = sb[0];
            cent[rank * 3 + 1] = sb[1];
            cent[rank * 3 + 2] = sb[2];
          }
        }
      }
    }
  }
}

// ---------------------------------------------------------------------------
extern "C" void kernel_launch(void* const* d_in, const int* in_sizes, int n_in,
                              void* d_out, int out_size, void* d_ws, size_t ws_size,
                              hipStream_t stream) {
  const float* xyz   = (const float*)d_in[0];
  const float* feat  = (const float*)d_in[1];
  const float* cla   = (const float*)d_in[2];
  const float* tmpl  = (const float*)d_in[3];
  const float* W1    = (const float*)d_in[4];
  const float* b1    = (const float*)d_in[5];
  const float* gamma = (const float*)d_in[6];
  const float* beta  = (const float*)d_in[7];
  const float* rmean = (const float*)d_in[8];
  const float* rvar  = (const float*)d_in[9];
  const float* W2    = (const float*)d_in[10];
  const float* b2    = (const float*)d_in[11];
  float* out  = (float*)d_out;
  float* prop = out + (size_t)NBATCH * NPOST * 7 + (size_t)NBATCH * NPOST; // 4096

  char* ws = (char*)d_ws;
  float* selbox  = (float*)(ws);                               // 8*900*8*4 = 230400
  float* corners = (float*)(ws + 230400);                      // 230400
  float* areas   = (float*)(ws + 460800);                      // 28800
  unsigned long long* sup   = (unsigned long long*)(ws + 489600);   // 921600
  unsigned long long* keepw = (unsigned long long*)(ws + 1411200);  // 1024

  mlp_kernel<<<dim3(NTOT / 128, NBATCH), 256, 0, stream>>>(
      feat, xyz, W1, b1, gamma, beta, rmean, rvar, W2, b2, prop);

  select_kernel<<<NBATCH, 1024, 0, stream>>>(cla, prop, tmpl, selbox, corners,
                                             areas);

  iou_kernel<<<dim3(NPRE, NBATCH), 256, 0, stream>>>(corners, areas, sup);

  (void)hipFuncSetAttribute((const void*)nms_kernel,
                            hipFuncAttributeMaxDynamicSharedMemorySize,
                            NMS_ROWS * 16 * (int)sizeof(unsigned long long));
  nms_kernel<<<NBATCH, 1024, NMS_ROWS * 16 * sizeof(unsigned long long),
               stream>>>(sup, keepw);

  out_kernel<<<NBATCH, 128, 0, stream>>>(selbox, keepw, out);
}